// Round 9
// baseline (416.445 us; speedup 1.0000x reference)
//
#include <hip/hip_runtime.h>

typedef _Float16 f16;
typedef f16 f16x2 __attribute__((ext_vector_type(2)));
typedef f16 f16x4 __attribute__((ext_vector_type(4)));
typedef f16 f16x8 __attribute__((ext_vector_type(8)));
typedef float f32x4 __attribute__((ext_vector_type(4)));
typedef float f32x16 __attribute__((ext_vector_type(16)));
typedef unsigned int u32;
typedef u32 u32x2 __attribute__((ext_vector_type(2)));
typedef u32 u32x4 __attribute__((ext_vector_type(4)));

#define MFMA32(a, b, c) __builtin_amdgcn_mfma_f32_32x32x16_f16((a), (b), (c), 0, 0, 0)

__device__ __forceinline__ u32 pk2(float a, float b) {
    return __builtin_bit_cast(u32, __builtin_amdgcn_cvt_pkrtz(a, b));
}
__device__ __forceinline__ f16x4 lo4(f16x8 v) { return __builtin_shufflevector(v, v, 0, 1, 2, 3); }
__device__ __forceinline__ f16x4 hi4(f16x8 v) { return __builtin_shufflevector(v, v, 4, 5, 6, 7); }

// C-frag (rows in regs, col on lanes) -> A/B-frag (same lane, 8 consecutive rows as elems).
__device__ __forceinline__ f16x8 xfrm(f32x16 v, int rb) {
    u32 a0 = pk2(v[rb + 0], v[rb + 1]);
    u32 a1 = pk2(v[rb + 2], v[rb + 3]);
    u32 b0 = pk2(v[rb + 4], v[rb + 5]);
    u32 b1 = pk2(v[rb + 6], v[rb + 7]);
    u32x2 r0 = __builtin_amdgcn_permlane32_swap(a0, b0, false, false);
    u32x2 r1 = __builtin_amdgcn_permlane32_swap(a1, b1, false, false);
    u32x4 aw = {r0.x, r1.x, r0.y, r1.y};
    return __builtin_bit_cast(f16x8, aw);
}
__device__ __forceinline__ f16x8 add8(f16x8 a, f16x8 b) {
    f16x8 r;
#pragma unroll
    for (int j = 0; j < 8; ++j) r[j] = a[j] + b[j];
    return r;
}

// ---------------- LDS layout for fallback fused kernel (bytes) ----------------
#define OFF_Y   65536
#define OFF_SST 98304
#define LDS_ATT 99328

// per-pass Wf stride in f16: 32768 W + 128 bias (bq f16[64], bk f16[64])
#define WSTRIDE 32896

// =====================================================================================
// repack: x fp32 [B,C,H,W] -> Xall f16 [b][n2=(i2,j2)][n1=(i1,j1)][c]
// =====================================================================================
__global__ __launch_bounds__(512) void repack_kernel(const float* __restrict__ x,
                                                     f16* __restrict__ Xall) {
    __shared__ f16 XT[128 * 264];     // [c][w], padded
    const int tid = threadIdx.x, g = blockIdx.x;
    const int b = g >> 8, i1 = (g >> 4) & 15, i2 = g & 15;
    const int h = i1 * 16 + i2;
    {
        const int c = tid >> 2, wq = (tid & 3) * 64;
        const float* src = x + (((size_t)b * 128 + c) * 256 + h) * 256 + wq;
        f16* dst = XT + c * 264 + wq;
#pragma unroll
        for (int i = 0; i < 16; ++i) {
            f32x4 v = *(const f32x4*)(src + i * 4);
            f16x4 o = {(f16)v[0], (f16)v[1], (f16)v[2], (f16)v[3]};
            *(f16x4*)(dst + i * 4) = o;
        }
    }
    __syncthreads();
    {
        const int w = tid >> 1, ch = (tid & 1) * 64;   // w = j1*16 + j2
        const int j1 = w >> 4, j2 = w & 15;
        f16* dst = Xall + (((size_t)b * 256 + i2 * 16 + j2) * 256 + i1 * 16 + j1) * 128 + ch;
#pragma unroll
        for (int i = 0; i < 8; ++i) {
            f16x8 v;
#pragma unroll
            for (int j = 0; j < 8; ++j) v[j] = XT[(ch + i * 8 + j) * 264 + w];
            *(f16x8*)(dst + i * 8) = v;
        }
    }
}

// =====================================================================================
// weight conversion fp32 -> f16, fragment-linear + f16 bias tail per pass
// =====================================================================================
__global__ void wconv_kernel(const float* __restrict__ w1x, const float* __restrict__ w1y,
                             const float* __restrict__ w1o, const float* __restrict__ b1x,
                             const float* __restrict__ b1y, const float* __restrict__ w2x,
                             const float* __restrict__ w2y, const float* __restrict__ w2o,
                             const float* __restrict__ b2x, const float* __restrict__ b2y,
                             f16* __restrict__ Wf) {
    int i = blockIdx.x * 256 + threadIdx.x;      // 65792 total
    if (i < 65536) {
        int p = i >> 15, idx = i & 32767;
        int j = idx & 7, lane = (idx >> 3) & 63, ks = (idx >> 9) & 7, r = idx >> 12;
        int row = r * 32 + (lane & 31);
        int c = ks * 16 + (lane >> 5) * 8 + j;
        const float* s;
        if (p == 0) s = (row < 128) ? w1o + row * 128 : (row < 192) ? w1x + (row - 128) * 128
                                                                   : w1y + (row - 192) * 128;
        else        s = (row < 128) ? w2o + row * 128 : (row < 192) ? w2x + (row - 128) * 128
                                                                   : w2y + (row - 192) * 128;
        Wf[p * WSTRIDE + idx] = (f16)s[c];
    } else {
        int idx2 = i - 65536;                    // 0..255
        int p = idx2 >> 7, r = idx2 & 127;
        const float* bsrc = (p == 0) ? ((r < 64) ? b1x : b1y) : ((r < 64) ? b2x : b2y);
        Wf[p * WSTRIDE + 32768 + r] = (f16)bsrc[r & 63];
    }
}

// =====================================================================================
// proj kernel (split pipeline, phase 1): per att-block g, compute theta^T, psi^T, V''
// fragments and store them fragment-linear to global. No LDS weight staging (W frags
// are L1/L2-hot). PASS1: TP overwrites Xall in place (block-local, barrier-protected).
// TP[g]: Th frags [tt*4+ks][l][8] then (+16384) Ps frags [kt*4+ks][l][8].
// Vf[g]: [slice 2*tt+ksl][ct][l][8].
// =====================================================================================
template <int PASS>
__global__ __launch_bounds__(512, 4) void proj_kernel(
    const f16* Xin, const f16* __restrict__ Wf, const float* __restrict__ bo,
    const float* __restrict__ bnab, f16* TP, f16* __restrict__ Vf) {
    const int tid = threadIdx.x, l = tid & 63, hl = l >> 5, l31 = l & 31;
    const int tt = tid >> 6, g = blockIdx.x;

    // ---- X frags: token t = tt*32+l31, elems c = ks*16 + hl*8 + j ----
    const f16* src = Xin + (size_t)g * 32768 + (tt * 32 + l31) * 128 + hl * 8;
    f16x8 afr[8];
#pragma unroll
    for (int ks = 0; ks < 8; ++ks) afr[ks] = *(const f16x8*)(src + ks * 16);
    if constexpr (PASS == 1) __syncthreads();   // all X reads done before TP overwrite
    if constexpr (PASS == 2) {                  // BN1 + ReLU on the fly
#pragma unroll
        for (int ks = 0; ks < 8; ++ks) {
            const int c0 = ks * 16 + hl * 8;
            f32x4 a0 = *(const f32x4*)(bnab + c0), a1 = *(const f32x4*)(bnab + c0 + 4);
            f32x4 s0 = *(const f32x4*)(bnab + 128 + c0), s1 = *(const f32x4*)(bnab + 132 + c0);
            f16x8 v = afr[ks];
#pragma unroll
            for (int j = 0; j < 4; ++j) {
                v[j]     = (f16)fmaxf(a0[j] * (float)v[j]     + s0[j], 0.f);
                v[j + 4] = (f16)fmaxf(a1[j] * (float)v[j + 4] + s1[j], 0.f);
            }
            afr[ks] = v;
        }
    }

    // ---- bias frags (f16, element m = ks*16 + hl*8 + j) ----
    const f16* bfp = Wf + 32768;
    f16x8 bqf[4], bkf[4];
#pragma unroll
    for (int ks = 0; ks < 4; ++ks) {
        bqf[ks] = *(const f16x8*)(bfp + ks * 16 + hl * 8);
        bkf[ks] = *(const f16x8*)(bfp + 64 + ks * 16 + hl * 8);
    }

    f16* tpg = TP + (size_t)g * 32768;

    // ---- theta^T = Wq . X^T (tiles 4-5) -> pack -> store Th ----
    {
        f32x16 aT[2] = {};
#pragma unroll
        for (int ks = 0; ks < 8; ++ks) {
            f16x8 wq0 = *(const f16x8*)(Wf + ((32 + ks) * 64 + l) * 8);
            f16x8 wq1 = *(const f16x8*)(Wf + ((40 + ks) * 64 + l) * 8);
            aT[0] = MFMA32(wq0, afr[ks], aT[0]);
            aT[1] = MFMA32(wq1, afr[ks], aT[1]);
        }
#pragma unroll
        for (int ks = 0; ks < 4; ++ks)
            *(f16x8*)(tpg + (tt * 4 + ks) * 512 + l * 8) =
                add8(xfrm(aT[ks >> 1], 8 * (ks & 1)), bqf[ks]);
    }

    // ---- psi^T = Wk . X^T (tiles 6-7) -> pack -> store Ps ----
    {
        f32x16 aP[2] = {};
#pragma unroll
        for (int ks = 0; ks < 8; ++ks) {
            f16x8 wk0 = *(const f16x8*)(Wf + ((48 + ks) * 64 + l) * 8);
            f16x8 wk1 = *(const f16x8*)(Wf + ((56 + ks) * 64 + l) * 8);
            aP[0] = MFMA32(wk0, afr[ks], aP[0]);
            aP[1] = MFMA32(wk1, afr[ks], aP[1]);
        }
#pragma unroll
        for (int ks = 0; ks < 4; ++ks)
            *(f16x8*)(tpg + 16384 + (tt * 4 + ks) * 512 + l * 8) =
                add8(xfrm(aP[ks >> 1], 8 * (ks & 1)), bkf[ks]);
    }

    // ---- V'' = X . Wo^T + bo (tiles 0-3), two ct at a time to cap registers ----
    f16* vfg = Vf + (size_t)g * 32768;
#pragma unroll
    for (int ch = 0; ch < 2; ++ch) {
        f32x16 aV[2] = {};
#pragma unroll
        for (int ks = 0; ks < 8; ++ks) {
            f16x8 wo0 = *(const f16x8*)(Wf + (((ch * 2 + 0) * 8 + ks) * 64 + l) * 8);
            f16x8 wo1 = *(const f16x8*)(Wf + (((ch * 2 + 1) * 8 + ks) * 64 + l) * 8);
            aV[0] = MFMA32(afr[ks], wo0, aV[0]);
            aV[1] = MFMA32(afr[ks], wo1, aV[1]);
        }
#pragma unroll
        for (int cc = 0; cc < 2; ++cc) {
            const int ct = ch * 2 + cc;
            float bov = bo[ct * 32 + l31];
#pragma unroll
            for (int e = 0; e < 16; ++e) aV[cc][e] += bov;
#pragma unroll
            for (int ksl = 0; ksl < 2; ++ksl)
                *(f16x8*)(vfg + (2 * tt + ksl) * 2048 + ct * 512 + l * 8) = xfrm(aV[cc], 8 * ksl);
        }
    }
}

// =====================================================================================
// attn kernel (split pipeline, phase 2): one wave per (g, tt), no barriers, no staging
// LDS. S^T = psi.theta (frags from global), full softmax, PV (V frags from global),
// BN stat partials, direct coalesced stores.
// =====================================================================================
template <int PASS>
__global__ __launch_bounds__(256, 2) void attn_kernel(
    const f16* __restrict__ TP, const f16* __restrict__ Vf, f16* __restrict__ Uout,
    float* __restrict__ gstats, int t_stride, int s_stride) {
    __shared__ float SST[256];
    const int tid = threadIdx.x, l = tid & 63, hl = l >> 5, l31 = l & 31;
    const int bid = blockIdx.x;
    const int g = (bid >> 4) * 8 + (bid & 7);        // paired blocks (bid, bid+8): same XCD
    const int tt = ((bid >> 3) & 1) * 4 + (tid >> 6);
    const int R0 = tt * 32;

    SST[tid] = 0.f;
    __syncthreads();

    const f16* tpg = TP + (size_t)g * 32768;

    // ---- theta B-frags ----
    f16x8 tb[4];
#pragma unroll
    for (int ks = 0; ks < 4; ++ks)
        tb[ks] = *(const f16x8*)(tpg + (tt * 4 + ks) * 512 + l * 8);

    // ---- S^T: col t = R0+l31 on lanes, all 256 k rows in regs ----
    f32x16 s[8] = {};
    __builtin_amdgcn_s_setprio(1);
#pragma unroll
    for (int kt = 0; kt < 8; ++kt)
#pragma unroll
        for (int ks = 0; ks < 4; ++ks) {
            f16x8 ay = *(const f16x8*)(tpg + 16384 + (kt * 4 + ks) * 512 + l * 8);
            s[kt] = MFMA32(ay, tb[ks], s[kt]);
        }
    __builtin_amdgcn_s_setprio(0);

    // ---- softmax over k: per-lane 128 values + hl-partner combine ----
    float mx = -1e30f;
#pragma unroll
    for (int kt = 0; kt < 8; ++kt) {
        float m0 = fmaxf(fmaxf(s[kt][0], s[kt][1]), fmaxf(s[kt][2], s[kt][3]));
        float m1 = fmaxf(fmaxf(s[kt][4], s[kt][5]), fmaxf(s[kt][6], s[kt][7]));
        float m2 = fmaxf(fmaxf(s[kt][8], s[kt][9]), fmaxf(s[kt][10], s[kt][11]));
        float m3 = fmaxf(fmaxf(s[kt][12], s[kt][13]), fmaxf(s[kt][14], s[kt][15]));
        mx = fmaxf(mx, fmaxf(fmaxf(m0, m1), fmaxf(m2, m3)));
    }
    mx = fmaxf(mx, __shfl_xor(mx, 32));
    float sum = 0.f;
#pragma unroll
    for (int kt = 0; kt < 8; ++kt)
#pragma unroll
        for (int e = 0; e < 16; ++e) {
            float p = __expf(s[kt][e] - mx);
            s[kt][e] = p;
            sum += p;
        }
    sum += __shfl_xor(sum, 32);
    const float rs = 1.f / sum;
#pragma unroll
    for (int kt = 0; kt < 8; ++kt)
#pragma unroll
        for (int e = 0; e < 16; ++e) s[kt][e] *= rs;

    // ---- PV: A-frags in-register (xfrm), B-frags from global Vf ----
    const f16* vfg = Vf + (size_t)g * 32768;
    f32x16 o[4] = {};
#pragma unroll
    for (int kt = 0; kt < 8; ++kt)
#pragma unroll
        for (int ks2 = 0; ks2 < 2; ++ks2) {
            f16x8 ap = xfrm(s[kt], 8 * ks2);
            __builtin_amdgcn_s_setprio(1);
#pragma unroll
            for (int ct = 0; ct < 4; ++ct) {
                f16x8 bv = *(const f16x8*)(vfg + ((kt * 2 + ks2) * 2048 + ct * 512 + l * 8));
                o[ct] = MFMA32(ap, bv, o[ct]);
            }
            __builtin_amdgcn_s_setprio(0);
        }

    // ---- BN stat partials ----
#pragma unroll
    for (int ct = 0; ct < 4; ++ct) {
        float ss = 0.f, sq = 0.f;
#pragma unroll
        for (int e = 0; e < 16; ++e) {
            float v = o[ct][e];
            ss += v;
            sq += v * v;
        }
        ss += __shfl_xor(ss, 32);
        sq += __shfl_xor(sq, 32);
        if (hl == 0) {
            atomicAdd(&SST[ct * 32 + l31], ss);
            atomicAdd(&SST[128 + ct * 32 + l31], sq);
        }
    }

    // ---- epilogue: direct 64B-segment stores from C-frags ----
    const size_t ub = (size_t)(g >> 8) * 8388608 + (size_t)(g & 255) * (size_t)s_stride;
#pragma unroll
    for (int r = 0; r < 16; ++r) {
        int trow = (r & 3) + 8 * (r >> 2) + 4 * hl;
        f16* rp = Uout + ub + (size_t)(R0 + trow) * (size_t)t_stride + l31;
#pragma unroll
        for (int ct = 0; ct < 4; ++ct) rp[ct * 32] = (f16)o[ct][r];
    }
    __syncthreads();
    atomicAdd(&gstats[tid], SST[tid]);
}

// =====================================================================================
// FALLBACK: R8 fused per-block attention (used only if ws_size is too small)
// =====================================================================================
template <int PASS>
__global__ __launch_bounds__(512, 2) void att_kernel(
    const f16* __restrict__ Xin, const f16* __restrict__ Wf, const float* __restrict__ bo,
    const float* __restrict__ bnab, f16* __restrict__ Uout, float* __restrict__ gstats,
    int t_stride, int s_stride) {
    __shared__ __align__(16) char smem[LDS_ATT];
    float* SST = (float*)(smem + OFF_SST);
    const int tid = threadIdx.x;
    const int w = tid >> 6, l = tid & 63, hl = l >> 5, l31 = l & 31;
    const int g = blockIdx.x, R0 = w * 32;

    if (tid < 256) SST[tid] = 0.f;

#pragma unroll
    for (int j = 0; j < 8; ++j) {
        int byte = (j * 512 + tid) * 16;
        *(f16x8*)(smem + byte) = *(const f16x8*)((const char*)Wf + byte);
    }

    const f16* src = Xin + (size_t)g * 32768 + (R0 + l31) * 128 + hl * 8;
    f16x8 afr[8];
#pragma unroll
    for (int ks = 0; ks < 8; ++ks) afr[ks] = *(const f16x8*)(src + ks * 16);
    if constexpr (PASS == 2) {
#pragma unroll
        for (int ks = 0; ks < 8; ++ks) {
            const int c0 = ks * 16 + hl * 8;
            f32x4 a0 = *(const f32x4*)(bnab + c0), a1 = *(const f32x4*)(bnab + c0 + 4);
            f32x4 s0 = *(const f32x4*)(bnab + 128 + c0), s1 = *(const f32x4*)(bnab + 132 + c0);
            f16x8 v = afr[ks];
#pragma unroll
            for (int j = 0; j < 4; ++j) {
                v[j]     = (f16)fmaxf(a0[j] * (float)v[j]     + s0[j], 0.f);
                v[j + 4] = (f16)fmaxf(a1[j] * (float)v[j + 4] + s1[j], 0.f);
            }
            afr[ks] = v;
        }
    }

    const f16* bfp = Wf + 32768;
    f16x8 bqf[4], bkf[4];
#pragma unroll
    for (int ks = 0; ks < 4; ++ks) {
        bqf[ks] = *(const f16x8*)(bfp + ks * 16 + hl * 8);
        bkf[ks] = *(const f16x8*)(bfp + 64 + ks * 16 + hl * 8);
    }
    __syncthreads();

    {
        f32x16 aP[2] = {};
#pragma unroll
        for (int ks = 0; ks < 8; ++ks)
#pragma unroll
            for (int mt = 0; mt < 2; ++mt) {
                f16x8 wk = *(const f16x8*)(smem + (((6 + mt) * 8 + ks) * 64 + l) * 16);
                aP[mt] = MFMA32(wk, afr[ks], aP[mt]);
            }
#pragma unroll
        for (int ks = 0; ks < 4; ++ks) {
            f16x8 yf = add8(xfrm(aP[ks >> 1], 8 * (ks & 1)), bkf[ks]);
            *(f16x8*)(smem + OFF_Y + ((w * 4 + ks) * 64 + l) * 16) = yf;
        }
    }

    f16x8 tb[4];
    {
        f32x16 aT[2] = {};
#pragma unroll
        for (int ks = 0; ks < 8; ++ks)
#pragma unroll
            for (int mt = 0; mt < 2; ++mt) {
                f16x8 wq = *(const f16x8*)(smem + (((4 + mt) * 8 + ks) * 64 + l) * 16);
                aT[mt] = MFMA32(wq, afr[ks], aT[mt]);
            }
#pragma unroll
        for (int ks = 0; ks < 4; ++ks)
            tb[ks] = add8(xfrm(aT[ks >> 1], 8 * (ks & 1)), bqf[ks]);
    }

    f32x16 aV[4] = {};
#pragma unroll
    for (int ks = 0; ks < 8; ++ks)
#pragma unroll
        for (int ct = 0; ct < 4; ++ct) {
            f16x8 wo = *(const f16x8*)(smem + ((ct * 8 + ks) * 64 + l) * 16);
            aV[ct] = MFMA32(afr[ks], wo, aV[ct]);
        }
#pragma unroll
    for (int ct = 0; ct < 4; ++ct) {
        float bov = bo[ct * 32 + l31];
#pragma unroll
        for (int e = 0; e < 16; ++e) aV[ct][e] += bov;
    }
    __syncthreads();

#pragma unroll
    for (int ct = 0; ct < 4; ++ct)
#pragma unroll
        for (int ksl = 0; ksl < 2; ++ksl)
            *(f16x8*)(smem + (((2 * w + ksl) * 4 + ct) * 64 + l) * 16) = xfrm(aV[ct], 8 * ksl);
    __syncthreads();

    f32x16 s[8] = {};
    __builtin_amdgcn_s_setprio(1);
#pragma unroll
    for (int kt = 0; kt < 8; ++kt)
#pragma unroll
        for (int ks = 0; ks < 4; ++ks) {
            f16x8 ay = *(const f16x8*)(smem + OFF_Y + ((kt * 4 + ks) * 64 + l) * 16);
            s[kt] = MFMA32(ay, tb[ks], s[kt]);
        }
    __builtin_amdgcn_s_setprio(0);

    float mx = -1e30f;
#pragma unroll
    for (int kt = 0; kt < 8; ++kt) {
        float m0 = fmaxf(fmaxf(s[kt][0], s[kt][1]), fmaxf(s[kt][2], s[kt][3]));
        float m1 = fmaxf(fmaxf(s[kt][4], s[kt][5]), fmaxf(s[kt][6], s[kt][7]));
        float m2 = fmaxf(fmaxf(s[kt][8], s[kt][9]), fmaxf(s[kt][10], s[kt][11]));
        float m3 = fmaxf(fmaxf(s[kt][12], s[kt][13]), fmaxf(s[kt][14], s[kt][15]));
        mx = fmaxf(mx, fmaxf(fmaxf(m0, m1), fmaxf(m2, m3)));
    }
    mx = fmaxf(mx, __shfl_xor(mx, 32));
    float sum = 0.f;
#pragma unroll
    for (int kt = 0; kt < 8; ++kt)
#pragma unroll
        for (int e = 0; e < 16; ++e) {
            float p = __expf(s[kt][e] - mx);
            s[kt][e] = p;
            sum += p;
        }
    sum += __shfl_xor(sum, 32);
    const float rs = 1.f / sum;
#pragma unroll
    for (int kt = 0; kt < 8; ++kt)
#pragma unroll
        for (int e = 0; e < 16; ++e) s[kt][e] *= rs;

    f32x16 o[4] = {};
#pragma unroll
    for (int kt = 0; kt < 8; ++kt)
#pragma unroll
        for (int ks2 = 0; ks2 < 2; ++ks2) {
            f16x8 ap = xfrm(s[kt], 8 * ks2);
            __builtin_amdgcn_s_setprio(1);
#pragma unroll
            for (int ct = 0; ct < 4; ++ct) {
                f16x8 bv = *(const f16x8*)(smem + (((kt * 2 + ks2) * 4 + ct) * 64 + l) * 16);
                o[ct] = MFMA32(ap, bv, o[ct]);
            }
            __builtin_amdgcn_s_setprio(0);
        }

#pragma unroll
    for (int ct = 0; ct < 4; ++ct) {
        float ss = 0.f, sq = 0.f;
#pragma unroll
        for (int e = 0; e < 16; ++e) {
            float v = o[ct][e];
            ss += v;
            sq += v * v;
        }
        ss += __shfl_xor(ss, 32);
        sq += __shfl_xor(sq, 32);
        if (hl == 0) {
            atomicAdd(&SST[ct * 32 + l31], ss);
            atomicAdd(&SST[128 + ct * 32 + l31], sq);
        }
    }

    const size_t ub = (size_t)(g >> 8) * 8388608 + (size_t)(g & 255) * (size_t)s_stride;
#pragma unroll
    for (int r = 0; r < 16; ++r) {
        int trow = (r & 3) + 8 * (r >> 2) + 4 * hl;
        f16* rp = Uout + ub + (size_t)(R0 + trow) * (size_t)t_stride + l31;
#pragma unroll
        for (int ct = 0; ct < 4; ++ct) rp[ct * 32] = (f16)o[ct][r];
    }
    __syncthreads();
    if (tid < 256) atomicAdd(&gstats[tid], SST[tid]);
}

// =====================================================================================
// BN stats finalize: (sum, sumsq) -> (a, b) with y = a*x + b
// =====================================================================================
__global__ void bnfix_kernel(const float* __restrict__ gstats, const float* __restrict__ gamma,
                             const float* __restrict__ beta, float* __restrict__ ab) {
    int c = threadIdx.x;
    if (c < 128) {
        const float inv = 1.f / 262144.f;
        float mean = gstats[c] * inv;
        float var = gstats[128 + c] * inv - mean * mean;
        float rstd = rsqrtf(var + 1e-5f);
        float a = gamma[c] * rstd;
        ab[c] = a;
        ab[128 + c] = beta[c] - mean * a;
    }
}

// =====================================================================================
// final: U2 f16 [b][n1][n2][c] -> BN2+ReLU -> out fp32 [B,C,H,W]
// =====================================================================================
__global__ __launch_bounds__(256) void final_kernel(const f16* __restrict__ U2,
                                                    const float* __restrict__ ab,
                                                    float* __restrict__ out) {
    __shared__ f16 L[256 * 132];      // [n2][c] padded
    const int tid = threadIdx.x, g = blockIdx.x;
    const int b = g >> 8, i1 = (g >> 4) & 15, j1 = g & 15;
    const f16* src = U2 + (size_t)g * 32768;
#pragma unroll
    for (int e = 0; e < 16; ++e) {
        int u = e * 2048 + tid * 8;
        int row = u >> 7, c0 = u & 127;
        f16x8 v = *(const f16x8*)(src + u);
        f16* dst = L + row * 132 + c0;
        *(f16x4*)dst = lo4(v);
        *(f16x4*)(dst + 4) = hi4(v);
    }
    __syncthreads();
    const int j2 = tid & 15, bu = tid >> 4;
#pragma unroll 4
    for (int k = 0; k < 128; ++k) {
        int unit = bu + k * 16;        // 0..2047 -> (c, i2)
        int c = unit & 127, i2 = unit >> 7;
        float a = ab[c], bb = ab[128 + c];
        float v = fmaxf(a * (float)L[(i2 * 16 + j2) * 132 + c] + bb, 0.f);
        out[(((size_t)b * 128 + c) * 256 + i1 * 16 + i2) * 256 + j1 * 16 + j2] = v;
    }
}

// =====================================================================================
extern "C" void kernel_launch(void* const* d_in, const int* in_sizes, int n_in, void* d_out,
                              int out_size, void* d_ws, size_t ws_size, hipStream_t stream) {
    (void)in_sizes; (void)n_in; (void)out_size;
    const float* x = (const float*)d_in[0];
    const float* w1x = (const float*)d_in[1];
    const float* b1x = (const float*)d_in[2];
    const float* w1y = (const float*)d_in[3];
    const float* b1y = (const float*)d_in[4];
    const float* w1o = (const float*)d_in[5];
    const float* b1o = (const float*)d_in[6];
    const float* g1 = (const float*)d_in[7];
    const float* be1 = (const float*)d_in[8];
    const float* w2x = (const float*)d_in[9];
    const float* b2x = (const float*)d_in[10];
    const float* w2y = (const float*)d_in[11];
    const float* b2y = (const float*)d_in[12];
    const float* w2o = (const float*)d_in[13];
    const float* b2o = (const float*)d_in[14];
    const float* g2 = (const float*)d_in[15];
    const float* be2 = (const float*)d_in[16];

    f16* Xall = (f16*)d_out;                               // [0,64MiB) of d_out
    f16* U1 = (f16*)((char*)d_out + 67108864);             // [64MiB,128MiB) of d_out

    if (ws_size >= (size_t)134500000) {
        // ---- split-pipeline path ----
        // d_out: Xall (becomes TP in place) | U1.  ws: Vf | U2 | Wbf | stats.
        f16* TP = (f16*)d_out;
        f16* Vfp = (f16*)d_ws;
        f16* U2 = (f16*)((char*)d_ws + 67108864);
        f16* Wbf = (f16*)((char*)d_ws + 134217728);
        float* gstats = (float*)((char*)d_ws + 134217728 + 131584);
        float* bnab = gstats + 512;

        (void)hipMemsetAsync(gstats, 0, 2048, stream);
        wconv_kernel<<<257, 256, 0, stream>>>(w1x, w1y, w1o, b1x, b1y, w2x, w2y, w2o, b2x, b2y,
                                              Wbf);
        repack_kernel<<<1024, 512, 0, stream>>>(x, Xall);

        proj_kernel<1><<<1024, 512, 0, stream>>>(Xall, Wbf, b1o, (const float*)nullptr, TP, Vfp);
        attn_kernel<1><<<2048, 256, 0, stream>>>(TP, Vfp, U1, gstats, 32768, 128);
        bnfix_kernel<<<1, 128, 0, stream>>>(gstats, g1, be1, bnab);

        proj_kernel<2><<<1024, 512, 0, stream>>>(U1, Wbf + WSTRIDE, b2o, bnab, TP, Vfp);
        attn_kernel<2><<<2048, 256, 0, stream>>>(TP, Vfp, U2, gstats + 256, 128, 32768);
        bnfix_kernel<<<1, 128, 0, stream>>>(gstats + 256, g2, be2, bnab + 256);

        final_kernel<<<1024, 256, 0, stream>>>(U2, bnab + 256, (float*)d_out);
    } else {
        // ---- fallback: proven R8 fused path ----
        f16* U2 = (f16*)d_ws;
        f16* Wbf = (f16*)((char*)d_ws + 67108864);
        float* gstats = (float*)((char*)d_ws + 67108864 + 262144);
        float* bnab = gstats + 512;

        (void)hipMemsetAsync(gstats, 0, 2048, stream);
        wconv_kernel<<<257, 256, 0, stream>>>(w1x, w1y, w1o, b1x, b1y, w2x, w2y, w2o, b2x, b2y,
                                              Wbf);
        repack_kernel<<<1024, 512, 0, stream>>>(x, Xall);

        att_kernel<1><<<1024, 512, 0, stream>>>(Xall, Wbf, b1o, (const float*)nullptr, U1, gstats,
                                                32768, 128);
        bnfix_kernel<<<1, 128, 0, stream>>>(gstats, g1, be1, bnab);
        att_kernel<2><<<1024, 512, 0, stream>>>(U1, Wbf + WSTRIDE, b2o, bnab, U2, gstats + 256,
                                                128, 32768);
        bnfix_kernel<<<1, 128, 0, stream>>>(gstats + 256, g2, be2, bnab + 256);
        final_kernel<<<1024, 256, 0, stream>>>(U2, bnab + 256, (float*)d_out);
    }
}

// Round 12
// 333.204 us; speedup vs baseline: 1.2498x; 1.2498x over previous
//
#include <hip/hip_runtime.h>

typedef _Float16 f16;
typedef f16 f16x2 __attribute__((ext_vector_type(2)));
typedef f16 f16x4 __attribute__((ext_vector_type(4)));
typedef f16 f16x8 __attribute__((ext_vector_type(8)));
typedef float f32x4 __attribute__((ext_vector_type(4)));
typedef float f32x16 __attribute__((ext_vector_type(16)));
typedef unsigned int u32;
typedef u32 u32x2 __attribute__((ext_vector_type(2)));
typedef u32 u32x4 __attribute__((ext_vector_type(4)));

#define MFMA32(a, b, c) __builtin_amdgcn_mfma_f32_32x32x16_f16((a), (b), (c), 0, 0, 0)

__device__ __forceinline__ u32 pk2(float a, float b) {
    return __builtin_bit_cast(u32, __builtin_amdgcn_cvt_pkrtz(a, b));
}
__device__ __forceinline__ f16x4 lo4(f16x8 v) { return __builtin_shufflevector(v, v, 0, 1, 2, 3); }
__device__ __forceinline__ f16x4 hi4(f16x8 v) { return __builtin_shufflevector(v, v, 4, 5, 6, 7); }

// C-frag (rows in regs, col on lanes) -> A/B-frag (same lane, 8 consecutive rows as elems).
__device__ __forceinline__ f16x8 xfrm(f32x16 v, int rb) {
    u32 a0 = pk2(v[rb + 0], v[rb + 1]);
    u32 a1 = pk2(v[rb + 2], v[rb + 3]);
    u32 b0 = pk2(v[rb + 4], v[rb + 5]);
    u32 b1 = pk2(v[rb + 6], v[rb + 7]);
    u32x2 r0 = __builtin_amdgcn_permlane32_swap(a0, b0, false, false);
    u32x2 r1 = __builtin_amdgcn_permlane32_swap(a1, b1, false, false);
    u32x4 aw = {r0.x, r1.x, r0.y, r1.y};
    return __builtin_bit_cast(f16x8, aw);
}
__device__ __forceinline__ f16x8 add8(f16x8 a, f16x8 b) {
    f16x8 r;
#pragma unroll
    for (int j = 0; j < 8; ++j) r[j] = a[j] + b[j];
    return r;
}

// ---------------- LDS layout (bytes): three DISJOINT regions, W persistent ----------
// [0,65536):        W fragment-linear [8 tiles][8 ks][64 lanes][16B] (never overwritten)
// [65536,98304):    Yf psi^T fragments [8 kt][4 ks][64][16B]; stat exchange after loop
// [98304,163840):   Vf V'' fragments [16 slices][4 ct][64][16B]
#define OFF_Y   65536
#define OFF_V   98304
#define LDS_ATT 163840

// per-pass Wf stride in f16: 32768 W + 128 bias (bq f16[64], bk f16[64])
#define WSTRIDE 32896

// =====================================================================================
// repack: x fp32 [B,C,H,W] -> Xall f16 [b][n2=(i2,j2)][n1=(i1,j1)][c]
// =====================================================================================
__global__ __launch_bounds__(512) void repack_kernel(const float* __restrict__ x,
                                                     f16* __restrict__ Xall) {
    __shared__ f16 XT[128 * 264];     // [c][w], padded
    const int tid = threadIdx.x, g = blockIdx.x;
    const int b = g >> 8, i1 = (g >> 4) & 15, i2 = g & 15;
    const int h = i1 * 16 + i2;
    {
        const int c = tid >> 2, wq = (tid & 3) * 64;
        const float* src = x + (((size_t)b * 128 + c) * 256 + h) * 256 + wq;
        f16* dst = XT + c * 264 + wq;
#pragma unroll
        for (int i = 0; i < 16; ++i) {
            f32x4 v = *(const f32x4*)(src + i * 4);
            f16x4 o = {(f16)v[0], (f16)v[1], (f16)v[2], (f16)v[3]};
            *(f16x4*)(dst + i * 4) = o;
        }
    }
    __syncthreads();
    {
        const int w = tid >> 1, ch = (tid & 1) * 64;   // w = j1*16 + j2
        const int j1 = w >> 4, j2 = w & 15;
        f16* dst = Xall + (((size_t)b * 256 + i2 * 16 + j2) * 256 + i1 * 16 + j1) * 128 + ch;
#pragma unroll
        for (int i = 0; i < 8; ++i) {
            f16x8 v;
#pragma unroll
            for (int j = 0; j < 8; ++j) v[j] = XT[(ch + i * 8 + j) * 264 + w];
            *(f16x8*)(dst + i * 8) = v;
        }
    }
}

// =====================================================================================
// weight conversion fp32 -> f16, fragment-linear + f16 bias tail per pass
// =====================================================================================
__global__ void wconv_kernel(const float* __restrict__ w1x, const float* __restrict__ w1y,
                             const float* __restrict__ w1o, const float* __restrict__ b1x,
                             const float* __restrict__ b1y, const float* __restrict__ w2x,
                             const float* __restrict__ w2y, const float* __restrict__ w2o,
                             const float* __restrict__ b2x, const float* __restrict__ b2y,
                             f16* __restrict__ Wf) {
    int i = blockIdx.x * 256 + threadIdx.x;      // 65792 total
    if (i < 65536) {
        int p = i >> 15, idx = i & 32767;
        int j = idx & 7, lane = (idx >> 3) & 63, ks = (idx >> 9) & 7, r = idx >> 12;
        int row = r * 32 + (lane & 31);
        int c = ks * 16 + (lane >> 5) * 8 + j;
        const float* s;
        if (p == 0) s = (row < 128) ? w1o + row * 128 : (row < 192) ? w1x + (row - 128) * 128
                                                                   : w1y + (row - 192) * 128;
        else        s = (row < 128) ? w2o + row * 128 : (row < 192) ? w2x + (row - 128) * 128
                                                                   : w2y + (row - 192) * 128;
        Wf[p * WSTRIDE + idx] = (f16)s[c];
    } else {
        int idx2 = i - 65536;                    // 0..255
        int p = idx2 >> 7, r = idx2 & 127;
        const float* bsrc = (p == 0) ? ((r < 64) ? b1x : b1y) : ((r < 64) ? b2x : b2y);
        Wf[p * WSTRIDE + 32768 + r] = (f16)bsrc[r & 63];
    }
}

// =====================================================================================
// fused per-block attention, persistent (4 att-blocks per workgroup), disjoint LDS,
// R8-exact per-iteration arithmetic (no prefetch, __expf softmax, pre-normalized P):
//   out = softmax(theta psi) @ (X Wo^T + bo)
// =====================================================================================
template <int PASS>
__global__ __launch_bounds__(512, 2) void att_kernel(
    const f16* __restrict__ Xin, const f16* __restrict__ Wf, const float* __restrict__ bo,
    const float* __restrict__ bnab, f16* __restrict__ Uout, float* __restrict__ gstats,
    int t_stride, int s_stride) {
    __shared__ __align__(16) char smem[LDS_ATT];
    const int tid = threadIdx.x;
    const int w = tid >> 6, l = tid & 63, hl = l >> 5, l31 = l & 31;
    const int R0 = w * 32;

    // ---- loop-invariant: bias frags, bo, stat accumulators ----
    const f16* bfp = Wf + 32768;
    f16x8 bqf[4], bkf[4];
#pragma unroll
    for (int ks = 0; ks < 4; ++ks) {
        bqf[ks] = *(const f16x8*)(bfp + ks * 16 + hl * 8);
        bkf[ks] = *(const f16x8*)(bfp + 64 + ks * 16 + hl * 8);
    }
    float bov[4];
#pragma unroll
    for (int ct = 0; ct < 4; ++ct) bov[ct] = bo[ct * 32 + l31];
    float ssa[4] = {0.f, 0.f, 0.f, 0.f}, sqa[4] = {0.f, 0.f, 0.f, 0.f};

    // ---- prologue: W -> LDS once ----
    {
        f16x8 wv[8];
#pragma unroll
        for (int j = 0; j < 8; ++j)
            wv[j] = *(const f16x8*)((const char*)Wf + (j * 512 + tid) * 16);
#pragma unroll
        for (int j = 0; j < 8; ++j)
            *(f16x8*)(smem + (j * 512 + tid) * 16) = wv[j];
    }
    __syncthreads();   // W resident

    for (int it = 0; it < 4; ++it) {
        const int g = blockIdx.x + it * 256;

        // ---- X load (R8-exact sequence: load -> BN -> use) ----
        f16x8 afr[8];
        {
            const f16* src = Xin + (size_t)g * 32768 + (R0 + l31) * 128 + hl * 8;
#pragma unroll
            for (int ks = 0; ks < 8; ++ks) afr[ks] = *(const f16x8*)(src + ks * 16);
        }
        if constexpr (PASS == 2) {
#pragma unroll
            for (int ks = 0; ks < 8; ++ks) {
                const int c0 = ks * 16 + hl * 8;
                f32x4 a0 = *(const f32x4*)(bnab + c0), a1 = *(const f32x4*)(bnab + c0 + 4);
                f32x4 s0 = *(const f32x4*)(bnab + 128 + c0), s1 = *(const f32x4*)(bnab + 132 + c0);
                f16x8 v = afr[ks];
#pragma unroll
                for (int j = 0; j < 4; ++j) {
                    v[j]     = (f16)fmaxf(a0[j] * (float)v[j]     + s0[j], 0.f);
                    v[j + 4] = (f16)fmaxf(a1[j] * (float)v[j + 4] + s1[j], 0.f);
                }
                afr[ks] = v;
            }
        }

        // ---- psi^T = Wk . X^T (tiles 6-7) -> Yf ----
        {
            f32x16 aP[2] = {};
#pragma unroll
            for (int ks = 0; ks < 8; ++ks)
#pragma unroll
                for (int mt = 0; mt < 2; ++mt) {
                    f16x8 wk = *(const f16x8*)(smem + (((6 + mt) * 8 + ks) * 64 + l) * 16);
                    aP[mt] = MFMA32(wk, afr[ks], aP[mt]);
                }
#pragma unroll
            for (int ks = 0; ks < 4; ++ks) {
                f16x8 yf = add8(xfrm(aP[ks >> 1], 8 * (ks & 1)), bkf[ks]);
                *(f16x8*)(smem + OFF_Y + ((w * 4 + ks) * 64 + l) * 16) = yf;
            }
        }

        // ---- theta^T = Wq . X^T (tiles 4-5) -> tb in-register ----
        f16x8 tb[4];
        {
            f32x16 aT[2] = {};
#pragma unroll
            for (int ks = 0; ks < 8; ++ks)
#pragma unroll
                for (int mt = 0; mt < 2; ++mt) {
                    f16x8 wq = *(const f16x8*)(smem + (((4 + mt) * 8 + ks) * 64 + l) * 16);
                    aT[mt] = MFMA32(wq, afr[ks], aT[mt]);
                }
#pragma unroll
            for (int ks = 0; ks < 4; ++ks)
                tb[ks] = add8(xfrm(aT[ks >> 1], 8 * (ks & 1)), bqf[ks]);
        }

        // ---- V'' = X . Wo^T + bo (tiles 0-3) -> pack -> Vf ----
        {
            f32x16 aV[4] = {};
#pragma unroll
            for (int ks = 0; ks < 8; ++ks)
#pragma unroll
                for (int ct = 0; ct < 4; ++ct) {
                    f16x8 wo = *(const f16x8*)(smem + ((ct * 8 + ks) * 64 + l) * 16);
                    aV[ct] = MFMA32(afr[ks], wo, aV[ct]);
                }
#pragma unroll
            for (int ct = 0; ct < 4; ++ct) {
#pragma unroll
                for (int e = 0; e < 16; ++e) aV[ct][e] += bov[ct];
#pragma unroll
                for (int ksl = 0; ksl < 2; ++ksl)
                    *(f16x8*)(smem + OFF_V + (((2 * w + ksl) * 4 + ct) * 64 + l) * 16) =
                        xfrm(aV[ct], 8 * ksl);
            }
        }
        __syncthreads();   // b1: Yf + Vf complete (W untouched)

        // ---- S^T: col t = R0+l31 on lanes, all 256 k rows in regs ----
        f32x16 s[8] = {};
        __builtin_amdgcn_s_setprio(1);
#pragma unroll
        for (int kt = 0; kt < 8; ++kt)
#pragma unroll
            for (int ks = 0; ks < 4; ++ks) {
                f16x8 ay = *(const f16x8*)(smem + OFF_Y + ((kt * 4 + ks) * 64 + l) * 16);
                s[kt] = MFMA32(ay, tb[ks], s[kt]);
            }
        __builtin_amdgcn_s_setprio(0);

        // ---- softmax over k (R8-exact: __expf, normalize before PV) ----
        float mx = -1e30f;
#pragma unroll
        for (int kt = 0; kt < 8; ++kt) {
            float m0 = fmaxf(fmaxf(s[kt][0], s[kt][1]), fmaxf(s[kt][2], s[kt][3]));
            float m1 = fmaxf(fmaxf(s[kt][4], s[kt][5]), fmaxf(s[kt][6], s[kt][7]));
            float m2 = fmaxf(fmaxf(s[kt][8], s[kt][9]), fmaxf(s[kt][10], s[kt][11]));
            float m3 = fmaxf(fmaxf(s[kt][12], s[kt][13]), fmaxf(s[kt][14], s[kt][15]));
            mx = fmaxf(mx, fmaxf(fmaxf(m0, m1), fmaxf(m2, m3)));
        }
        mx = fmaxf(mx, __shfl_xor(mx, 32));
        float sum = 0.f;
#pragma unroll
        for (int kt = 0; kt < 8; ++kt)
#pragma unroll
            for (int e = 0; e < 16; ++e) {
                float p = __expf(s[kt][e] - mx);
                s[kt][e] = p;
                sum += p;
            }
        sum += __shfl_xor(sum, 32);
        const float rs = 1.f / sum;
#pragma unroll
        for (int kt = 0; kt < 8; ++kt)
#pragma unroll
            for (int e = 0; e < 16; ++e) s[kt][e] *= rs;

        // ---- PV: A-frags in-register (xfrm), B from Vf ----
        f32x16 o[4] = {};
#pragma unroll
        for (int kt = 0; kt < 8; ++kt)
#pragma unroll
            for (int ks2 = 0; ks2 < 2; ++ks2) {
                f16x8 ap = xfrm(s[kt], 8 * ks2);
                __builtin_amdgcn_s_setprio(1);
#pragma unroll
                for (int ct = 0; ct < 4; ++ct) {
                    f16x8 bv =
                        *(const f16x8*)(smem + OFF_V + (((kt * 2 + ks2) * 4 + ct) * 64 + l) * 16);
                    o[ct] = MFMA32(ap, bv, o[ct]);
                }
                __builtin_amdgcn_s_setprio(0);
            }

        // ---- epilogue: BN stats into registers, coalesced stores ----
        const size_t ub = (size_t)(g >> 8) * 8388608 + (size_t)(g & 255) * (size_t)s_stride;
#pragma unroll
        for (int ct = 0; ct < 4; ++ct) {
            float ss = 0.f, sq = 0.f;
#pragma unroll
            for (int e = 0; e < 16; ++e) {
                float v = o[ct][e];
                ss += v;
                sq += v * v;
            }
            ssa[ct] += ss;
            sqa[ct] += sq;
        }
#pragma unroll
        for (int r = 0; r < 16; ++r) {
            int trow = (r & 3) + 8 * (r >> 2) + 4 * hl;
            f16* rp = Uout + ub + (size_t)(R0 + trow) * (size_t)t_stride + l31;
#pragma unroll
            for (int ct = 0; ct < 4; ++ct) rp[ct * 32] = (f16)o[ct][r];
        }
        __syncthreads();   // b0: all Yf/Vf reads done before next iteration's writes
    }

    // ---- final BN-stat reduction via dead Yf region ----
#pragma unroll
    for (int ct = 0; ct < 4; ++ct) {
        ssa[ct] += __shfl_xor(ssa[ct], 32);
        sqa[ct] += __shfl_xor(sqa[ct], 32);
    }
    float* SS = (float*)(smem + OFF_Y);   // [2][8][128]
    if (hl == 0) {
#pragma unroll
        for (int ct = 0; ct < 4; ++ct) {
            SS[w * 128 + ct * 32 + l31] = ssa[ct];
            SS[1024 + w * 128 + ct * 32 + l31] = sqa[ct];
        }
    }
    __syncthreads();
    if (tid < 256) {
        int c = tid & 127, which = tid >> 7;
        float acc = 0.f;
#pragma unroll
        for (int iw = 0; iw < 8; ++iw) acc += SS[which * 1024 + iw * 128 + c];
        atomicAdd(&gstats[which * 128 + c], acc);
    }
}

// =====================================================================================
// BN stats finalize: (sum, sumsq) -> (a, b) with y = a*x + b
// =====================================================================================
__global__ void bnfix_kernel(const float* __restrict__ gstats, const float* __restrict__ gamma,
                             const float* __restrict__ beta, float* __restrict__ ab) {
    int c = threadIdx.x;
    if (c < 128) {
        const float inv = 1.f / 262144.f;
        float mean = gstats[c] * inv;
        float var = gstats[128 + c] * inv - mean * mean;
        float rstd = rsqrtf(var + 1e-5f);
        float a = gamma[c] * rstd;
        ab[c] = a;
        ab[128 + c] = beta[c] - mean * a;
    }
}

// =====================================================================================
// final: U2 f16 [b][n1][n2][c] -> BN2+ReLU -> out fp32 [B,C,H,W]
// =====================================================================================
__global__ __launch_bounds__(256) void final_kernel(const f16* __restrict__ U2,
                                                    const float* __restrict__ ab,
                                                    float* __restrict__ out) {
    __shared__ f16 L[256 * 132];      // [n2][c] padded
    const int tid = threadIdx.x, g = blockIdx.x;
    const int b = g >> 8, i1 = (g >> 4) & 15, j1 = g & 15;
    const f16* src = U2 + (size_t)g * 32768;
#pragma unroll
    for (int e = 0; e < 16; ++e) {
        int u = e * 2048 + tid * 8;
        int row = u >> 7, c0 = u & 127;
        f16x8 v = *(const f16x8*)(src + u);
        f16* dst = L + row * 132 + c0;
        *(f16x4*)dst = lo4(v);
        *(f16x4*)(dst + 4) = hi4(v);
    }
    __syncthreads();
    const int j2 = tid & 15, bu = tid >> 4;
#pragma unroll 4
    for (int k = 0; k < 128; ++k) {
        int unit = bu + k * 16;        // 0..2047 -> (c, i2)
        int c = unit & 127, i2 = unit >> 7;
        float a = ab[c], bb = ab[128 + c];
        float v = fmaxf(a * (float)L[(i2 * 16 + j2) * 132 + c] + bb, 0.f);
        out[(((size_t)b * 128 + c) * 256 + i1 * 16 + i2) * 256 + j1 * 16 + j2] = v;
    }
}

// =====================================================================================
extern "C" void kernel_launch(void* const* d_in, const int* in_sizes, int n_in, void* d_out,
                              int out_size, void* d_ws, size_t ws_size, hipStream_t stream) {
    (void)in_sizes; (void)n_in; (void)out_size; (void)ws_size;
    const float* x = (const float*)d_in[0];
    const float* w1x = (const float*)d_in[1];
    const float* b1x = (const float*)d_in[2];
    const float* w1y = (const float*)d_in[3];
    const float* b1y = (const float*)d_in[4];
    const float* w1o = (const float*)d_in[5];
    const float* b1o = (const float*)d_in[6];
    const float* g1 = (const float*)d_in[7];
    const float* be1 = (const float*)d_in[8];
    const float* w2x = (const float*)d_in[9];
    const float* b2x = (const float*)d_in[10];
    const float* w2y = (const float*)d_in[11];
    const float* b2y = (const float*)d_in[12];
    const float* w2o = (const float*)d_in[13];
    const float* b2o = (const float*)d_in[14];
    const float* g2 = (const float*)d_in[15];
    const float* be2 = (const float*)d_in[16];

    // d_out doubles as scratch: [0,64MiB) Xall f16, [64MiB,128MiB) U1 f16 (both dead
    // before final_kernel rewrites d_out as fp32).
    f16* Xall = (f16*)d_out;
    f16* U1 = (f16*)((char*)d_out + 67108864);
    f16* U2 = (f16*)d_ws;
    f16* Wbf = (f16*)((char*)d_ws + 67108864);                  // [2][WSTRIDE] f16
    float* gstats = (float*)((char*)d_ws + 67108864 + 262144);  // [2][256]
    float* bnab = gstats + 512;                                 // [2][256]

    (void)hipMemsetAsync(gstats, 0, 2048, stream);
    wconv_kernel<<<257, 256, 0, stream>>>(w1x, w1y, w1o, b1x, b1y, w2x, w2y, w2o, b2x, b2y, Wbf);
    repack_kernel<<<1024, 512, 0, stream>>>(x, Xall);

    att_kernel<1><<<256, 512, 0, stream>>>(Xall, Wbf, b1o, (const float*)nullptr, U1, gstats,
                                           32768, 128);
    bnfix_kernel<<<1, 128, 0, stream>>>(gstats, g1, be1, bnab);
    att_kernel<2><<<256, 512, 0, stream>>>(U1, Wbf + WSTRIDE, b2o, bnab, U2, gstats + 256, 128,
                                           32768);
    bnfix_kernel<<<1, 128, 0, stream>>>(gstats + 256, g2, be2, bnab + 256);
    final_kernel<<<1024, 256, 0, stream>>>(U2, bnab + 256, (float*)d_out);
}

// Round 13
// 260.333 us; speedup vs baseline: 1.5997x; 1.2799x over previous
//
#include <hip/hip_runtime.h>

typedef _Float16 f16;
typedef f16 f16x2 __attribute__((ext_vector_type(2)));
typedef f16 f16x4 __attribute__((ext_vector_type(4)));
typedef f16 f16x8 __attribute__((ext_vector_type(8)));
typedef float f32x4 __attribute__((ext_vector_type(4)));
typedef float f32x16 __attribute__((ext_vector_type(16)));
typedef unsigned int u32;
typedef u32 u32x2 __attribute__((ext_vector_type(2)));
typedef u32 u32x4 __attribute__((ext_vector_type(4)));

#define MFMA32(a, b, c) __builtin_amdgcn_mfma_f32_32x32x16_f16((a), (b), (c), 0, 0, 0)

__device__ __forceinline__ u32 pk2(float a, float b) {
    return __builtin_bit_cast(u32, __builtin_amdgcn_cvt_pkrtz(a, b));
}
__device__ __forceinline__ f16x4 lo4(f16x8 v) { return __builtin_shufflevector(v, v, 0, 1, 2, 3); }
__device__ __forceinline__ f16x4 hi4(f16x8 v) { return __builtin_shufflevector(v, v, 4, 5, 6, 7); }

// C-frag (rows in regs, col on lanes) -> A/B-frag (same lane, 8 consecutive rows as elems).
__device__ __forceinline__ f16x8 xfrm(f32x16 v, int rb) {
    u32 a0 = pk2(v[rb + 0], v[rb + 1]);
    u32 a1 = pk2(v[rb + 2], v[rb + 3]);
    u32 b0 = pk2(v[rb + 4], v[rb + 5]);
    u32 b1 = pk2(v[rb + 6], v[rb + 7]);
    u32x2 r0 = __builtin_amdgcn_permlane32_swap(a0, b0, false, false);
    u32x2 r1 = __builtin_amdgcn_permlane32_swap(a1, b1, false, false);
    u32x4 aw = {r0.x, r1.x, r0.y, r1.y};
    return __builtin_bit_cast(f16x8, aw);
}
__device__ __forceinline__ f16x8 add8(f16x8 a, f16x8 b) {
    f16x8 r;
#pragma unroll
    for (int j = 0; j < 8; ++j) r[j] = a[j] + b[j];
    return r;
}

// R8 fused kernel LDS (aliased W/Vf) ----------------------------------------
#define OFF_Y8   65536
#define OFF_SST8 98304
#define LDS_ATT8 99328
// disjoint-LDS variant ------------------------------------------------------
#define AD_OFF_Y 65536
#define AD_OFF_V 98304
#define AD_LDS   163840

// per-pass Wf stride in f16: 32768 W + 128 bias (bq f16[64], bk f16[64])
#define WSTRIDE 32896

// =====================================================================================
// repack: x fp32 [B,C,H,W] -> Xall f16 [b][n2=(i2,j2)][n1=(i1,j1)][c]
// =====================================================================================
__global__ __launch_bounds__(512) void repack_kernel(const float* __restrict__ x,
                                                     f16* __restrict__ Xall) {
    __shared__ f16 XT[128 * 264];     // [c][w], padded
    const int tid = threadIdx.x, g = blockIdx.x;
    const int b = g >> 8, i1 = (g >> 4) & 15, i2 = g & 15;
    const int h = i1 * 16 + i2;
    {
        const int c = tid >> 2, wq = (tid & 3) * 64;
        const float* src = x + (((size_t)b * 128 + c) * 256 + h) * 256 + wq;
        f16* dst = XT + c * 264 + wq;
#pragma unroll
        for (int i = 0; i < 16; ++i) {
            f32x4 v = *(const f32x4*)(src + i * 4);
            f16x4 o = {(f16)v[0], (f16)v[1], (f16)v[2], (f16)v[3]};
            *(f16x4*)(dst + i * 4) = o;
        }
    }
    __syncthreads();
    {
        const int w = tid >> 1, ch = (tid & 1) * 64;   // w = j1*16 + j2
        const int j1 = w >> 4, j2 = w & 15;
        f16* dst = Xall + (((size_t)b * 256 + i2 * 16 + j2) * 256 + i1 * 16 + j1) * 128 + ch;
#pragma unroll
        for (int i = 0; i < 8; ++i) {
            f16x8 v;
#pragma unroll
            for (int j = 0; j < 8; ++j) v[j] = XT[(ch + i * 8 + j) * 264 + w];
            *(f16x8*)(dst + i * 8) = v;
        }
    }
}

// =====================================================================================
// weight conversion fp32 -> f16, fragment-linear + f16 bias tail per pass
// =====================================================================================
__global__ void wconv_kernel(const float* __restrict__ w1x, const float* __restrict__ w1y,
                             const float* __restrict__ w1o, const float* __restrict__ b1x,
                             const float* __restrict__ b1y, const float* __restrict__ w2x,
                             const float* __restrict__ w2y, const float* __restrict__ w2o,
                             const float* __restrict__ b2x, const float* __restrict__ b2y,
                             f16* __restrict__ Wf) {
    int i = blockIdx.x * 256 + threadIdx.x;      // 65792 total
    if (i < 65536) {
        int p = i >> 15, idx = i & 32767;
        int j = idx & 7, lane = (idx >> 3) & 63, ks = (idx >> 9) & 7, r = idx >> 12;
        int row = r * 32 + (lane & 31);
        int c = ks * 16 + (lane >> 5) * 8 + j;
        const float* s;
        if (p == 0) s = (row < 128) ? w1o + row * 128 : (row < 192) ? w1x + (row - 128) * 128
                                                                   : w1y + (row - 192) * 128;
        else        s = (row < 128) ? w2o + row * 128 : (row < 192) ? w2x + (row - 128) * 128
                                                                   : w2y + (row - 192) * 128;
        Wf[p * WSTRIDE + idx] = (f16)s[c];
    } else {
        int idx2 = i - 65536;                    // 0..255
        int p = idx2 >> 7, r = idx2 & 127;
        const float* bsrc = (p == 0) ? ((r < 64) ? b1x : b1y) : ((r < 64) ? b2x : b2y);
        Wf[p * WSTRIDE + 32768 + r] = (f16)bsrc[r & 63];
    }
}

// =====================================================================================
// attd: disjoint-LDS non-persistent fused attention (A/B experiment, used for pass 1).
// W(64K) + Yf(32K) + Vf(64K) disjoint; 2 heavy barriers; register BN-stats.
// =====================================================================================
template <int PASS>
__global__ __launch_bounds__(512, 2) void attd_kernel(
    const f16* __restrict__ Xin, const f16* __restrict__ Wf, const float* __restrict__ bo,
    const float* __restrict__ bnab, f16* __restrict__ Uout, float* __restrict__ gstats,
    int t_stride, int s_stride) {
    __shared__ __align__(16) char smem[AD_LDS];
    const int tid = threadIdx.x;
    const int w = tid >> 6, l = tid & 63, hl = l >> 5, l31 = l & 31;
    const int g = blockIdx.x, R0 = w * 32;

    const f16* bfp = Wf + 32768;
    f16x8 bqf[4], bkf[4];
#pragma unroll
    for (int ks = 0; ks < 4; ++ks) {
        bqf[ks] = *(const f16x8*)(bfp + ks * 16 + hl * 8);
        bkf[ks] = *(const f16x8*)(bfp + 64 + ks * 16 + hl * 8);
    }
    float bov[4];
#pragma unroll
    for (int ct = 0; ct < 4; ++ct) bov[ct] = bo[ct * 32 + l31];

    // ---- prologue: W -> LDS, X -> afr (loads overlap) ----
    f16x8 afr[8];
    {
        f16x8 wv[8];
#pragma unroll
        for (int j = 0; j < 8; ++j)
            wv[j] = *(const f16x8*)((const char*)Wf + (j * 512 + tid) * 16);
        const f16* src = Xin + (size_t)g * 32768 + (R0 + l31) * 128 + hl * 8;
#pragma unroll
        for (int ks = 0; ks < 8; ++ks) afr[ks] = *(const f16x8*)(src + ks * 16);
        if constexpr (PASS == 2) {
#pragma unroll
            for (int ks = 0; ks < 8; ++ks) {
                const int c0 = ks * 16 + hl * 8;
                f32x4 a0 = *(const f32x4*)(bnab + c0), a1 = *(const f32x4*)(bnab + c0 + 4);
                f32x4 s0 = *(const f32x4*)(bnab + 128 + c0), s1 = *(const f32x4*)(bnab + 132 + c0);
                f16x8 v = afr[ks];
#pragma unroll
                for (int j = 0; j < 4; ++j) {
                    v[j]     = (f16)fmaxf(a0[j] * (float)v[j]     + s0[j], 0.f);
                    v[j + 4] = (f16)fmaxf(a1[j] * (float)v[j + 4] + s1[j], 0.f);
                }
                afr[ks] = v;
            }
        }
#pragma unroll
        for (int j = 0; j < 8; ++j)
            *(f16x8*)(smem + (j * 512 + tid) * 16) = wv[j];
    }
    __syncthreads();   // b0: W resident

    // ---- psi^T (tiles 6-7) -> Yf ----
    {
        f32x16 aP[2] = {};
#pragma unroll
        for (int ks = 0; ks < 8; ++ks)
#pragma unroll
            for (int mt = 0; mt < 2; ++mt) {
                f16x8 wk = *(const f16x8*)(smem + (((6 + mt) * 8 + ks) * 64 + l) * 16);
                aP[mt] = MFMA32(wk, afr[ks], aP[mt]);
            }
#pragma unroll
        for (int ks = 0; ks < 4; ++ks) {
            f16x8 yf = add8(xfrm(aP[ks >> 1], 8 * (ks & 1)), bkf[ks]);
            *(f16x8*)(smem + AD_OFF_Y + ((w * 4 + ks) * 64 + l) * 16) = yf;
        }
    }

    // ---- theta^T (tiles 4-5) -> tb in-register ----
    f16x8 tb[4];
    {
        f32x16 aT[2] = {};
#pragma unroll
        for (int ks = 0; ks < 8; ++ks)
#pragma unroll
            for (int mt = 0; mt < 2; ++mt) {
                f16x8 wq = *(const f16x8*)(smem + (((4 + mt) * 8 + ks) * 64 + l) * 16);
                aT[mt] = MFMA32(wq, afr[ks], aT[mt]);
            }
#pragma unroll
        for (int ks = 0; ks < 4; ++ks)
            tb[ks] = add8(xfrm(aT[ks >> 1], 8 * (ks & 1)), bqf[ks]);
    }

    // ---- V'' (tiles 0-3) -> pack -> Vf ----
    {
        f32x16 aV[4] = {};
#pragma unroll
        for (int ks = 0; ks < 8; ++ks)
#pragma unroll
            for (int ct = 0; ct < 4; ++ct) {
                f16x8 wo = *(const f16x8*)(smem + ((ct * 8 + ks) * 64 + l) * 16);
                aV[ct] = MFMA32(afr[ks], wo, aV[ct]);
            }
#pragma unroll
        for (int ct = 0; ct < 4; ++ct) {
#pragma unroll
            for (int e = 0; e < 16; ++e) aV[ct][e] += bov[ct];
#pragma unroll
            for (int ksl = 0; ksl < 2; ++ksl)
                *(f16x8*)(smem + AD_OFF_V + (((2 * w + ksl) * 4 + ct) * 64 + l) * 16) =
                    xfrm(aV[ct], 8 * ksl);
        }
    }
    __syncthreads();   // b1: Yf + Vf complete

    // ---- S^T ----
    f32x16 s[8] = {};
    __builtin_amdgcn_s_setprio(1);
#pragma unroll
    for (int kt = 0; kt < 8; ++kt)
#pragma unroll
        for (int ks = 0; ks < 4; ++ks) {
            f16x8 ay = *(const f16x8*)(smem + AD_OFF_Y + ((kt * 4 + ks) * 64 + l) * 16);
            s[kt] = MFMA32(ay, tb[ks], s[kt]);
        }
    __builtin_amdgcn_s_setprio(0);

    // ---- softmax (R8-exact) ----
    float mx = -1e30f;
#pragma unroll
    for (int kt = 0; kt < 8; ++kt) {
        float m0 = fmaxf(fmaxf(s[kt][0], s[kt][1]), fmaxf(s[kt][2], s[kt][3]));
        float m1 = fmaxf(fmaxf(s[kt][4], s[kt][5]), fmaxf(s[kt][6], s[kt][7]));
        float m2 = fmaxf(fmaxf(s[kt][8], s[kt][9]), fmaxf(s[kt][10], s[kt][11]));
        float m3 = fmaxf(fmaxf(s[kt][12], s[kt][13]), fmaxf(s[kt][14], s[kt][15]));
        mx = fmaxf(mx, fmaxf(fmaxf(m0, m1), fmaxf(m2, m3)));
    }
    mx = fmaxf(mx, __shfl_xor(mx, 32));
    float sum = 0.f;
#pragma unroll
    for (int kt = 0; kt < 8; ++kt)
#pragma unroll
        for (int e = 0; e < 16; ++e) {
            float p = __expf(s[kt][e] - mx);
            s[kt][e] = p;
            sum += p;
        }
    sum += __shfl_xor(sum, 32);
    const float rs = 1.f / sum;
#pragma unroll
    for (int kt = 0; kt < 8; ++kt)
#pragma unroll
        for (int e = 0; e < 16; ++e) s[kt][e] *= rs;

    // ---- PV ----
    f32x16 o[4] = {};
#pragma unroll
    for (int kt = 0; kt < 8; ++kt)
#pragma unroll
        for (int ks2 = 0; ks2 < 2; ++ks2) {
            f16x8 ap = xfrm(s[kt], 8 * ks2);
            __builtin_amdgcn_s_setprio(1);
#pragma unroll
            for (int ct = 0; ct < 4; ++ct) {
                f16x8 bv =
                    *(const f16x8*)(smem + AD_OFF_V + (((kt * 2 + ks2) * 4 + ct) * 64 + l) * 16);
                o[ct] = MFMA32(ap, bv, o[ct]);
            }
            __builtin_amdgcn_s_setprio(0);
        }

    // ---- BN stats (registers) + stores ----
    float ssa[4], sqa[4];
#pragma unroll
    for (int ct = 0; ct < 4; ++ct) {
        float ss = 0.f, sq = 0.f;
#pragma unroll
        for (int e = 0; e < 16; ++e) {
            float v = o[ct][e];
            ss += v;
            sq += v * v;
        }
        ssa[ct] = ss + __shfl_xor(ss, 32);
        sqa[ct] = sq + __shfl_xor(sq, 32);
    }
    const size_t ub = (size_t)(g >> 8) * 8388608 + (size_t)(g & 255) * (size_t)s_stride;
#pragma unroll
    for (int r = 0; r < 16; ++r) {
        int trow = (r & 3) + 8 * (r >> 2) + 4 * hl;
        f16* rp = Uout + ub + (size_t)(R0 + trow) * (size_t)t_stride + l31;
#pragma unroll
        for (int ct = 0; ct < 4; ++ct) rp[ct * 32] = (f16)o[ct][r];
    }
    __syncthreads();   // b2: all Yf/Vf reads done

    float* SS = (float*)(smem + AD_OFF_Y);   // [2][8][128]
    if (hl == 0) {
#pragma unroll
        for (int ct = 0; ct < 4; ++ct) {
            SS[w * 128 + ct * 32 + l31] = ssa[ct];
            SS[1024 + w * 128 + ct * 32 + l31] = sqa[ct];
        }
    }
    __syncthreads();   // b3
    if (tid < 256) {
        int c = tid & 127, which = tid >> 7;
        float acc = 0.f;
#pragma unroll
        for (int iw = 0; iw < 8; ++iw) acc += SS[which * 1024 + iw * 128 + c];
        atomicAdd(&gstats[which * 128 + c], acc);
    }
}

// =====================================================================================
// att: R8-exact fused attention (proven 90 us; used for pass 2)
// =====================================================================================
template <int PASS>
__global__ __launch_bounds__(512, 2) void att_kernel(
    const f16* __restrict__ Xin, const f16* __restrict__ Wf, const float* __restrict__ bo,
    const float* __restrict__ bnab, f16* __restrict__ Uout, float* __restrict__ gstats,
    int t_stride, int s_stride) {
    __shared__ __align__(16) char smem[LDS_ATT8];
    float* SST = (float*)(smem + OFF_SST8);
    const int tid = threadIdx.x;
    const int w = tid >> 6, l = tid & 63, hl = l >> 5, l31 = l & 31;
    const int g = blockIdx.x, R0 = w * 32;

    if (tid < 256) SST[tid] = 0.f;

#pragma unroll
    for (int j = 0; j < 8; ++j) {
        int byte = (j * 512 + tid) * 16;
        *(f16x8*)(smem + byte) = *(const f16x8*)((const char*)Wf + byte);
    }

    const f16* src = Xin + (size_t)g * 32768 + (R0 + l31) * 128 + hl * 8;
    f16x8 afr[8];
#pragma unroll
    for (int ks = 0; ks < 8; ++ks) afr[ks] = *(const f16x8*)(src + ks * 16);
    if constexpr (PASS == 2) {
#pragma unroll
        for (int ks = 0; ks < 8; ++ks) {
            const int c0 = ks * 16 + hl * 8;
            f32x4 a0 = *(const f32x4*)(bnab + c0), a1 = *(const f32x4*)(bnab + c0 + 4);
            f32x4 s0 = *(const f32x4*)(bnab + 128 + c0), s1 = *(const f32x4*)(bnab + 132 + c0);
            f16x8 v = afr[ks];
#pragma unroll
            for (int j = 0; j < 4; ++j) {
                v[j]     = (f16)fmaxf(a0[j] * (float)v[j]     + s0[j], 0.f);
                v[j + 4] = (f16)fmaxf(a1[j] * (float)v[j + 4] + s1[j], 0.f);
            }
            afr[ks] = v;
        }
    }

    const f16* bfp = Wf + 32768;
    f16x8 bqf[4], bkf[4];
#pragma unroll
    for (int ks = 0; ks < 4; ++ks) {
        bqf[ks] = *(const f16x8*)(bfp + ks * 16 + hl * 8);
        bkf[ks] = *(const f16x8*)(bfp + 64 + ks * 16 + hl * 8);
    }
    __syncthreads();

    {
        f32x16 aP[2] = {};
#pragma unroll
        for (int ks = 0; ks < 8; ++ks)
#pragma unroll
            for (int mt = 0; mt < 2; ++mt) {
                f16x8 wk = *(const f16x8*)(smem + (((6 + mt) * 8 + ks) * 64 + l) * 16);
                aP[mt] = MFMA32(wk, afr[ks], aP[mt]);
            }
#pragma unroll
        for (int ks = 0; ks < 4; ++ks) {
            f16x8 yf = add8(xfrm(aP[ks >> 1], 8 * (ks & 1)), bkf[ks]);
            *(f16x8*)(smem + OFF_Y8 + ((w * 4 + ks) * 64 + l) * 16) = yf;
        }
    }

    f16x8 tb[4];
    {
        f32x16 aT[2] = {};
#pragma unroll
        for (int ks = 0; ks < 8; ++ks)
#pragma unroll
            for (int mt = 0; mt < 2; ++mt) {
                f16x8 wq = *(const f16x8*)(smem + (((4 + mt) * 8 + ks) * 64 + l) * 16);
                aT[mt] = MFMA32(wq, afr[ks], aT[mt]);
            }
#pragma unroll
        for (int ks = 0; ks < 4; ++ks)
            tb[ks] = add8(xfrm(aT[ks >> 1], 8 * (ks & 1)), bqf[ks]);
    }

    f32x16 aV[4] = {};
#pragma unroll
    for (int ks = 0; ks < 8; ++ks)
#pragma unroll
        for (int ct = 0; ct < 4; ++ct) {
            f16x8 wo = *(const f16x8*)(smem + ((ct * 8 + ks) * 64 + l) * 16);
            aV[ct] = MFMA32(afr[ks], wo, aV[ct]);
        }
#pragma unroll
    for (int ct = 0; ct < 4; ++ct) {
        float bov = bo[ct * 32 + l31];
#pragma unroll
        for (int e = 0; e < 16; ++e) aV[ct][e] += bov;
    }
    __syncthreads();

#pragma unroll
    for (int ct = 0; ct < 4; ++ct)
#pragma unroll
        for (int ksl = 0; ksl < 2; ++ksl)
            *(f16x8*)(smem + (((2 * w + ksl) * 4 + ct) * 64 + l) * 16) = xfrm(aV[ct], 8 * ksl);
    __syncthreads();

    f32x16 s[8] = {};
    __builtin_amdgcn_s_setprio(1);
#pragma unroll
    for (int kt = 0; kt < 8; ++kt)
#pragma unroll
        for (int ks = 0; ks < 4; ++ks) {
            f16x8 ay = *(const f16x8*)(smem + OFF_Y8 + ((kt * 4 + ks) * 64 + l) * 16);
            s[kt] = MFMA32(ay, tb[ks], s[kt]);
        }
    __builtin_amdgcn_s_setprio(0);

    float mx = -1e30f;
#pragma unroll
    for (int kt = 0; kt < 8; ++kt) {
        float m0 = fmaxf(fmaxf(s[kt][0], s[kt][1]), fmaxf(s[kt][2], s[kt][3]));
        float m1 = fmaxf(fmaxf(s[kt][4], s[kt][5]), fmaxf(s[kt][6], s[kt][7]));
        float m2 = fmaxf(fmaxf(s[kt][8], s[kt][9]), fmaxf(s[kt][10], s[kt][11]));
        float m3 = fmaxf(fmaxf(s[kt][12], s[kt][13]), fmaxf(s[kt][14], s[kt][15]));
        mx = fmaxf(mx, fmaxf(fmaxf(m0, m1), fmaxf(m2, m3)));
    }
    mx = fmaxf(mx, __shfl_xor(mx, 32));
    float sum = 0.f;
#pragma unroll
    for (int kt = 0; kt < 8; ++kt)
#pragma unroll
        for (int e = 0; e < 16; ++e) {
            float p = __expf(s[kt][e] - mx);
            s[kt][e] = p;
            sum += p;
        }
    sum += __shfl_xor(sum, 32);
    const float rs = 1.f / sum;
#pragma unroll
    for (int kt = 0; kt < 8; ++kt)
#pragma unroll
        for (int e = 0; e < 16; ++e) s[kt][e] *= rs;

    f32x16 o[4] = {};
#pragma unroll
    for (int kt = 0; kt < 8; ++kt)
#pragma unroll
        for (int ks2 = 0; ks2 < 2; ++ks2) {
            f16x8 ap = xfrm(s[kt], 8 * ks2);
            __builtin_amdgcn_s_setprio(1);
#pragma unroll
            for (int ct = 0; ct < 4; ++ct) {
                f16x8 bv = *(const f16x8*)(smem + (((kt * 2 + ks2) * 4 + ct) * 64 + l) * 16);
                o[ct] = MFMA32(ap, bv, o[ct]);
            }
            __builtin_amdgcn_s_setprio(0);
        }

#pragma unroll
    for (int ct = 0; ct < 4; ++ct) {
        float ss = 0.f, sq = 0.f;
#pragma unroll
        for (int e = 0; e < 16; ++e) {
            float v = o[ct][e];
            ss += v;
            sq += v * v;
        }
        ss += __shfl_xor(ss, 32);
        sq += __shfl_xor(sq, 32);
        if (hl == 0) {
            atomicAdd(&SST[ct * 32 + l31], ss);
            atomicAdd(&SST[128 + ct * 32 + l31], sq);
        }
    }

    const size_t ub = (size_t)(g >> 8) * 8388608 + (size_t)(g & 255) * (size_t)s_stride;
#pragma unroll
    for (int r = 0; r < 16; ++r) {
        int trow = (r & 3) + 8 * (r >> 2) + 4 * hl;
        f16* rp = Uout + ub + (size_t)(R0 + trow) * (size_t)t_stride + l31;
#pragma unroll
        for (int ct = 0; ct < 4; ++ct) rp[ct * 32] = (f16)o[ct][r];
    }
    __syncthreads();
    if (tid < 256) atomicAdd(&gstats[tid], SST[tid]);
}

// =====================================================================================
// BN stats finalize: (sum, sumsq) -> (a, b) with y = a*x + b
// =====================================================================================
__global__ void bnfix_kernel(const float* __restrict__ gstats, const float* __restrict__ gamma,
                             const float* __restrict__ beta, float* __restrict__ ab) {
    int c = threadIdx.x;
    if (c < 128) {
        const float inv = 1.f / 262144.f;
        float mean = gstats[c] * inv;
        float var = gstats[128 + c] * inv - mean * mean;
        float rstd = rsqrtf(var + 1e-5f);
        float a = gamma[c] * rstd;
        ab[c] = a;
        ab[128 + c] = beta[c] - mean * a;
    }
}

// =====================================================================================
// final: U2 f16 [b][n1][n2][c] -> BN2+ReLU -> out fp32 [B,C,H,W], f32x4 stores
// =====================================================================================
__global__ __launch_bounds__(256) void final_kernel(const f16* __restrict__ U2,
                                                    const float* __restrict__ ab,
                                                    float* __restrict__ out) {
    __shared__ f16 L[256 * 132];      // [n2][c] padded
    const int tid = threadIdx.x, g = blockIdx.x;
    const int b = g >> 8, i1 = (g >> 4) & 15, j1 = g & 15;
    const f16* src = U2 + (size_t)g * 32768;
#pragma unroll
    for (int e = 0; e < 16; ++e) {
        int u = e * 2048 + tid * 8;
        int row = u >> 7, c0 = u & 127;
        f16x8 v = *(const f16x8*)(src + u);
        f16* dst = L + row * 132 + c0;
        *(f16x4*)dst = lo4(v);
        *(f16x4*)(dst + 4) = hi4(v);
    }
    __syncthreads();
    const int j2q = tid & 3, u0 = tid >> 2;
#pragma unroll 4
    for (int k = 0; k < 32; ++k) {
        int unit = u0 + k * 64;        // 0..2047 -> (c, i2)
        int c = unit & 127, i2 = unit >> 7;
        float a = ab[c], bb = ab[128 + c];
        f32x4 vv;
#pragma unroll
        for (int jj = 0; jj < 4; ++jj)
            vv[jj] = fmaxf(a * (float)L[(i2 * 16 + j2q * 4 + jj) * 132 + c] + bb, 0.f);
        *(f32x4*)(out + (((size_t)b * 128 + c) * 256 + i1 * 16 + i2) * 256 + j1 * 16 + j2q * 4) =
            vv;
    }
}

// =====================================================================================
extern "C" void kernel_launch(void* const* d_in, const int* in_sizes, int n_in, void* d_out,
                              int out_size, void* d_ws, size_t ws_size, hipStream_t stream) {
    (void)in_sizes; (void)n_in; (void)out_size; (void)ws_size;
    const float* x = (const float*)d_in[0];
    const float* w1x = (const float*)d_in[1];
    const float* b1x = (const float*)d_in[2];
    const float* w1y = (const float*)d_in[3];
    const float* b1y = (const float*)d_in[4];
    const float* w1o = (const float*)d_in[5];
    const float* b1o = (const float*)d_in[6];
    const float* g1 = (const float*)d_in[7];
    const float* be1 = (const float*)d_in[8];
    const float* w2x = (const float*)d_in[9];
    const float* b2x = (const float*)d_in[10];
    const float* w2y = (const float*)d_in[11];
    const float* b2y = (const float*)d_in[12];
    const float* w2o = (const float*)d_in[13];
    const float* b2o = (const float*)d_in[14];
    const float* g2 = (const float*)d_in[15];
    const float* be2 = (const float*)d_in[16];

    // d_out doubles as scratch: [0,64MiB) Xall f16, [64MiB,128MiB) U1 f16 (both dead
    // before final_kernel rewrites d_out as fp32).
    f16* Xall = (f16*)d_out;
    f16* U1 = (f16*)((char*)d_out + 67108864);
    f16* U2 = (f16*)d_ws;
    f16* Wbf = (f16*)((char*)d_ws + 67108864);                  // [2][WSTRIDE] f16
    float* gstats = (float*)((char*)d_ws + 67108864 + 262144);  // [2][256]
    float* bnab = gstats + 512;                                 // [2][256]

    (void)hipMemsetAsync(gstats, 0, 2048, stream);
    wconv_kernel<<<257, 256, 0, stream>>>(w1x, w1y, w1o, b1x, b1y, w2x, w2y, w2o, b2x, b2y, Wbf);
    repack_kernel<<<1024, 512, 0, stream>>>(x, Xall);

    attd_kernel<1><<<1024, 512, 0, stream>>>(Xall, Wbf, b1o, (const float*)nullptr, U1, gstats,
                                             32768, 128);
    bnfix_kernel<<<1, 128, 0, stream>>>(gstats, g1, be1, bnab);
    att_kernel<2><<<1024, 512, 0, stream>>>(U1, Wbf + WSTRIDE, b2o, bnab, U2, gstats + 256, 128,
                                            32768);
    bnfix_kernel<<<1, 128, 0, stream>>>(gstats + 256, g2, be2, bnab + 256);
    final_kernel<<<1024, 256, 0, stream>>>(U2, bnab + 256, (float*)d_out);
}